// Round 2
// baseline (2501.557 us; speedup 1.0000x reference)
//
#include <hip/hip_runtime.h>

#define N_PTS 131072
#define NSEG 128

typedef unsigned short u16;
typedef __attribute__((ext_vector_type(8))) short short8;
typedef __attribute__((ext_vector_type(4))) float f32x4;

__device__ __forceinline__ u16 f2b(float f) {
  unsigned u = __float_as_uint(f);
  u += 0x7FFFu + ((u >> 16) & 1u);   // round-to-nearest-even
  return (u16)(u >> 16);
}

// ---------------- segment bounds ----------------
__global__ void k_init_bounds(int* beg, int* end) {
  int t = threadIdx.x;
  if (t < NSEG) { beg[t] = N_PTS; end[t] = 0; }
}
__global__ void k_bounds(const int* __restrict__ seg, int* beg, int* end) {
  int i = blockIdx.x * 256 + threadIdx.x;
  int s = seg[i];
  atomicMin(&beg[s], i);
  atomicMax(&end[s], i + 1);
}

// ---------------- input layer: h = lrelu(x @ W0 + b0), K=3 ----------------
__global__ __launch_bounds__(256) void k_in0(const float* __restrict__ x,
                                             const float* __restrict__ W0,
                                             const float* __restrict__ b0,
                                             float* __restrict__ Y) {
  int gid = blockIdx.x * 256 + threadIdx.x;
  int n = gid >> 7, c = gid & 127;
  float acc = b0[c];
  acc += x[n * 3 + 0] * W0[c];
  acc += x[n * 3 + 1] * W0[128 + c];
  acc += x[n * 3 + 2] * W0[256 + c];
  Y[gid] = acc > 0.f ? acc : 0.01f * acc;
}

// ---------------- GEMM: Y = act(bf16(X) @ bf16(W) + b), [N,128]@[128,128] ----------------
// ACT: 0 = none, 1 = lrelu(0.01). In-place safe (Y may alias X): each block
// stages its own 128 rows to LDS before storing, and touches only those rows.
template<int ACT>
__global__ __launch_bounds__(256) void k_gemm(const float* X,
                                              const float* __restrict__ W,
                                              const float* __restrict__ Bv,
                                              float* Y) {
  __shared__ u16 Xs[128 * 136];   // +8 bf16 pad per row: 2-way bank alias (free)
  const int tid = threadIdx.x;
  const int wave = tid >> 6, lane = tid & 63;
  const int q = lane >> 4, m16 = lane & 15;
  const int row0 = blockIdx.x * 128;

  // stage X (fp32 -> bf16) into LDS, coalesced float4
  const float4* X4 = (const float4*)(X + (size_t)row0 * 128);
  #pragma unroll
  for (int i = 0; i < 16; i++) {
    int f4 = i * 256 + tid;            // 0..4095
    int r = f4 >> 5, c4 = (f4 & 31) << 2;
    float4 v = X4[f4];
    ushort4 h;
    h.x = f2b(v.x); h.y = f2b(v.y); h.z = f2b(v.z); h.w = f2b(v.w);
    *(ushort4*)&Xs[r * 136 + c4] = h;
  }

  // persistent B fragments: wave covers cols wave*32 .. wave*32+31
  // B[k][n]: n = lane&15 (+tile base), k = quad*8 + j (+kc*32)
  short8 bf[2][4];
  #pragma unroll
  for (int ct = 0; ct < 2; ct++) {
    int n = wave * 32 + ct * 16 + m16;
    #pragma unroll
    for (int kc = 0; kc < 4; kc++)
      #pragma unroll
      for (int j = 0; j < 8; j++)
        bf[ct][kc][j] = (short)f2b(W[(kc * 32 + q * 8 + j) * 128 + n]);
  }
  float bias0 = Bv[wave * 32 + m16];
  float bias1 = Bv[wave * 32 + 16 + m16];
  __syncthreads();

  for (int rt = 0; rt < 8; rt++) {
    int r0 = rt * 16;
    // A[m][k]: m = lane&15, k = quad*8 + j  -> contiguous 16B in LDS
    short8 af[4];
    #pragma unroll
    for (int kc = 0; kc < 4; kc++)
      af[kc] = *(const short8*)&Xs[(r0 + m16) * 136 + kc * 32 + q * 8];
    f32x4 acc0 = {0.f, 0.f, 0.f, 0.f}, acc1 = {0.f, 0.f, 0.f, 0.f};
    #pragma unroll
    for (int kc = 0; kc < 4; kc++) {
      acc0 = __builtin_amdgcn_mfma_f32_16x16x32_bf16(af[kc], bf[0][kc], acc0, 0, 0, 0);
      acc1 = __builtin_amdgcn_mfma_f32_16x16x32_bf16(af[kc], bf[1][kc], acc1, 0, 0, 0);
    }
    // D: col = lane&15 (+ct*16), row = quad*4 + t
    #pragma unroll
    for (int t = 0; t < 4; t++) {
      int rr = row0 + r0 + q * 4 + t;
      float v0 = acc0[t] + bias0;
      float v1 = acc1[t] + bias1;
      if (ACT == 1) {
        v0 = v0 > 0.f ? v0 : 0.01f * v0;
        v1 = v1 > 0.f ? v1 : 0.01f * v1;
      }
      int c0 = rr * 128 + wave * 32 + m16;
      Y[c0] = v0;
      Y[c0 + 16] = v1;
    }
  }
}

// ---------------- ACN: block = segment, 1024 threads ----------------
// Y = relu((X - mean)*istd) [+ Hres];  a = e*wp / max(Swp, 1e-3*Z)
template<bool RES, bool WA>
__global__ __launch_bounds__(1024) void k_acn(const float* X, const float* __restrict__ Hres,
                                              float* Y,
                                              const float* __restrict__ attW,
                                              const float* __restrict__ attb,
                                              const float* __restrict__ wp,
                                              const int* __restrict__ beg_,
                                              const int* __restrict__ end_,
                                              float* __restrict__ L,
                                              float* __restrict__ a_out) {
  const int s = blockIdx.x;
  const int beg = beg_[s], end = end_[s];
  const int tid = threadIdx.x, wave = tid >> 6, lane = tid & 63;
  __shared__ float awS[128];
  __shared__ float redM[16], redA[16], redB[16];
  __shared__ float s1[1024], s2[1024];
  __shared__ float meanS[128], istdS[128];
  if (tid < 128) awS[tid] = attW[tid];
  const float ab = attb[0];
  __syncthreads();

  // phase 1: logits (wave per row) + running max
  float vmax = -3.4e38f;
  for (int r = beg + wave; r < end; r += 16) {
    float p = X[r * 128 + lane] * awS[lane] + X[r * 128 + 64 + lane] * awS[64 + lane];
    #pragma unroll
    for (int o = 32; o > 0; o >>= 1) p += __shfl_xor(p, o, 64);
    p += ab;
    if (lane == 0) L[r] = p;
    vmax = fmaxf(vmax, p);
  }
  if (lane == 0) redM[wave] = vmax;
  __syncthreads();
  float m = -3.4e38f;
  #pragma unroll
  for (int i = 0; i < 16; i++) m = fmaxf(m, redM[i]);

  // phase 2: e = exp(logit - m); Z = sum(e), Swp = sum(e*wp)
  float se = 0.f, sw = 0.f;
  for (int r = beg + tid; r < end; r += 1024) {
    float e = __expf(L[r] - m);
    se += e;
    sw += e * wp[r];
    L[r] = e;
  }
  #pragma unroll
  for (int o = 32; o > 0; o >>= 1) { se += __shfl_xor(se, o, 64); sw += __shfl_xor(sw, o, 64); }
  if (lane == 0) { redA[wave] = se; redB[wave] = sw; }
  __syncthreads();
  float Z = 0.f, Swp = 0.f;
  #pragma unroll
  for (int i = 0; i < 16; i++) { Z += redA[i]; Swp += redB[i]; }
  const float invd = 1.f / fmaxf(Swp, 1e-3f * Z);
  const float sa = Swp * invd;   // = seg_sum(a)

  // phase 3: per-channel weighted sums
  const int c = tid & 127, half = tid >> 7;   // 8 row-groups
  float sax = 0.f, sax2 = 0.f;
  for (int r = beg + half; r < end; r += 8) {
    float a = L[r] * wp[r] * invd;
    float xv = X[r * 128 + c];
    float ax = a * xv;
    sax += ax; sax2 += ax * xv;
  }
  s1[tid] = sax; s2[tid] = sax2;
  __syncthreads();
  if (half == 0) {
    float mean = 0.f, m2 = 0.f;
    #pragma unroll
    for (int h = 0; h < 8; h++) { mean += s1[c + 128 * h]; m2 += s2[c + 128 * h]; }
    float var = m2 - 2.f * mean * mean + mean * mean * sa;
    meanS[c] = mean;
    istdS[c] = 1.f / sqrtf(var + 1e-3f);
  }
  __syncthreads();

  // phase 4: normalize + relu (+ residual) [+ write a]
  for (int r = beg + half; r < end; r += 8) {
    float xv = X[r * 128 + c];
    float v = (xv - meanS[c]) * istdS[c];
    v = fmaxf(v, 0.f);
    if (RES) v += Hres[r * 128 + c];
    Y[r * 128 + c] = v;
    if (WA && c == 0) a_out[r] = L[r] * wp[r] * invd;
  }
}

// ---------------- launch ----------------
extern "C" void kernel_launch(void* const* d_in, const int* in_sizes, int n_in,
                              void* d_out, int out_size, void* d_ws, size_t ws_size,
                              hipStream_t stream) {
  const float* x     = (const float*)d_in[0];
  const int*   seg   = (const int*)d_in[1];
  const float* wp    = (const float*)d_in[2];
  const float* Win0  = (const float*)d_in[3];
  const float* bin0  = (const float*)d_in[4];
  const float* Wr    = (const float*)d_in[5];
  const float* br    = (const float*)d_in[6];
  const float* convW = (const float*)d_in[7];
  const float* convb = (const float*)d_in[8];
  const float* attW  = (const float*)d_in[9];
  const float* attb  = (const float*)d_in[10];
  const float* outW  = (const float*)d_in[11];
  const float* outb  = (const float*)d_in[12];

  // Buffers: A0 in d_ws; A1 is d_out's h-region (final GEMM lands there).
  float* A0 = (float*)d_ws;
  float* L  = A0 + (size_t)N_PTS * 128;
  int* beg  = (int*)(L + N_PTS);
  int* end  = beg + NSEG;
  float* A1    = (float*)d_out;                       // N*128 floats
  float* a_out = (float*)d_out + (size_t)N_PTS * 128; // N floats

  k_init_bounds<<<1, 128, 0, stream>>>(beg, end);
  k_bounds<<<N_PTS / 256, 256, 0, stream>>>(seg, beg, end);
  k_in0<<<N_PTS * 128 / 256, 256, 0, stream>>>(x, Win0, bin0, A0);

  for (int i = 0; i < 4; i++)  // 3 lrelu layers + (final linear, then outer lrelu)
    k_gemm<1><<<N_PTS / 128, 256, 0, stream>>>(A0, Wr + i * 128 * 128, br + i * 128, A0);

  float* h = A0; float* t = A1;
  for (int li = 0; li < 6; li++) {
    k_gemm<0><<<N_PTS / 128, 256, 0, stream>>>(h, convW + (li * 2 + 0) * 128 * 128,
                                               convb + (li * 2 + 0) * 128, t);
    k_acn<false, false><<<NSEG, 1024, 0, stream>>>(t, nullptr, t, attW + (li * 2 + 0) * 128,
                                                   attb + (li * 2 + 0), wp, beg, end, L, nullptr);
    k_gemm<0><<<N_PTS / 128, 256, 0, stream>>>(t, convW + (li * 2 + 1) * 128 * 128,
                                               convb + (li * 2 + 1) * 128, t);
    if (li == 5)
      k_acn<true, true><<<NSEG, 1024, 0, stream>>>(t, h, t, attW + (li * 2 + 1) * 128,
                                                   attb + (li * 2 + 1), wp, beg, end, L, a_out);
    else
      k_acn<true, false><<<NSEG, 1024, 0, stream>>>(t, h, t, attW + (li * 2 + 1) * 128,
                                                    attb + (li * 2 + 1), wp, beg, end, L, nullptr);
    float* tmp = h; h = t; t = tmp;
  }
  // h == A0 here (6 swaps from A0)

  k_gemm<1><<<N_PTS / 128, 256, 0, stream>>>(A0, outW, outb, A0);
  k_gemm<0><<<N_PTS / 128, 256, 0, stream>>>(A0, outW + 128 * 128, outb + 128, A1);
}

// Round 3
// 1166.043 us; speedup vs baseline: 2.1453x; 2.1453x over previous
//
#include <hip/hip_runtime.h>

#define N_PTS 131072
#define NSEG 128

typedef unsigned short u16;
typedef __attribute__((ext_vector_type(8))) short short8;
typedef __attribute__((ext_vector_type(4))) float f32x4;

__device__ __forceinline__ u16 f2b(float f) {
  unsigned u = __float_as_uint(f);
  u += 0x7FFFu + ((u >> 16) & 1u);   // round-to-nearest-even
  return (u16)(u >> 16);
}

// ---------------- segment bounds: sorted boundary scan (no atomics) ----------------
// beg has NSEG+1 entries; end[s] == beg[s+1].
__global__ __launch_bounds__(256) void k_bounds2(const int* __restrict__ seg, int* __restrict__ beg) {
  int i = blockIdx.x * 256 + threadIdx.x;
  int sc = seg[i];
  int sp = (i == 0) ? -1 : seg[i - 1];
  for (int s = sp + 1; s <= sc; s++) beg[s] = i;
  if (i == N_PTS - 1)
    for (int s = sc + 1; s <= NSEG; s++) beg[s] = N_PTS;
}

// ---------------- pack 18 weight matrices into bf16 transposed layout ----------------
// Wf[mat][n*128 + k] = bf16(W[mat][k*128 + n])  (so a B-fragment is 8 contiguous shorts)
__global__ __launch_bounds__(256) void k_wpack(const float* __restrict__ Wr,
                                               const float* __restrict__ convW,
                                               const float* __restrict__ outW,
                                               u16* __restrict__ Wf) {
  int mat = blockIdx.x;
  const float* W = (mat < 4) ? (Wr + mat * 16384)
                 : (mat < 16) ? (convW + (mat - 4) * 16384)
                              : (outW + (mat - 16) * 16384);
  u16* dst = Wf + mat * 16384;
  for (int t = threadIdx.x; t < 16384; t += 256) {
    int n = t >> 7, k = t & 127;
    dst[t] = f2b(W[k * 128 + n]);
  }
}

// ---------------- input layer: h = lrelu(x @ W0 + b0), K=3 ----------------
__global__ __launch_bounds__(256) void k_in0(const float* __restrict__ x,
                                             const float* __restrict__ W0,
                                             const float* __restrict__ b0,
                                             float* __restrict__ Y) {
  int gid = blockIdx.x * 256 + threadIdx.x;
  int n = gid >> 7, c = gid & 127;
  float acc = b0[c];
  acc += x[n * 3 + 0] * W0[c];
  acc += x[n * 3 + 1] * W0[128 + c];
  acc += x[n * 3 + 2] * W0[256 + c];
  Y[gid] = acc > 0.f ? acc : 0.01f * acc;
}

// ---------------- GEMM: Y = act(bf16(pre(X)) @ Wf + b), [N,128]@[128,128] ----------------
// ACT: 0 none, 1 lrelu.  LOGIT: also emit Lout[r] = Y[r]·attW + attb.
// FUSE: normalize+relu X during staging using ACN stats (meanA/m2A/segsa).
// In-place safe (Y may alias X): block stages its 128 rows to LDS before storing.
template<int ACT, bool LOGIT, bool FUSE>
__global__ __launch_bounds__(256) void k_gemm(const float* X,
                                              const u16* __restrict__ Wf,
                                              const float* __restrict__ Bv,
                                              float* Y,
                                              const float* __restrict__ attW,
                                              const float* __restrict__ attb,
                                              float* __restrict__ Lout,
                                              const int* __restrict__ seg,
                                              const float* __restrict__ meanA,
                                              const float* __restrict__ m2A,
                                              const float* __restrict__ segsa) {
  __shared__ u16 Xs[128 * 136];   // +8 bf16 pad per row (2-way bank alias: free)
  __shared__ float rowL[512];     // per-wave logit partials
  const int tid = threadIdx.x;
  const int wave = tid >> 6, lane = tid & 63;
  const int q = lane >> 4, m16 = lane & 15;
  const int row0 = blockIdx.x * 128;

  // stage X (fp32 -> bf16, optional fused ACN normalize+relu), coalesced float4
  const float4* X4 = (const float4*)(X + (size_t)row0 * 128);
  #pragma unroll
  for (int i = 0; i < 16; i++) {
    int f4 = i * 256 + tid;            // 0..4095
    int rloc = f4 >> 5, c4 = (f4 & 31) << 2;
    float4 v = X4[f4];
    if (FUSE) {
      int s = seg[row0 + rloc];
      float sa = segsa[s];
      float4 mn = *(const float4*)&meanA[s * 128 + c4];
      float4 m2 = *(const float4*)&m2A[s * 128 + c4];
      v.x = fmaxf((v.x - mn.x) * rsqrtf(m2.x + (sa - 2.f) * mn.x * mn.x + 1e-3f), 0.f);
      v.y = fmaxf((v.y - mn.y) * rsqrtf(m2.y + (sa - 2.f) * mn.y * mn.y + 1e-3f), 0.f);
      v.z = fmaxf((v.z - mn.z) * rsqrtf(m2.z + (sa - 2.f) * mn.z * mn.z + 1e-3f), 0.f);
      v.w = fmaxf((v.w - mn.w) * rsqrtf(m2.w + (sa - 2.f) * mn.w * mn.w + 1e-3f), 0.f);
    }
    ushort4 h;
    h.x = f2b(v.x); h.y = f2b(v.y); h.z = f2b(v.z); h.w = f2b(v.w);
    *(ushort4*)&Xs[rloc * 136 + c4] = h;
  }

  // B fragments: 16B vector loads from packed layout.
  // B[k][n]: n = lane&15 (+tile), k = quad*8+j (+kc*32)
  short8 bf[2][4];
  #pragma unroll
  for (int ct = 0; ct < 2; ct++) {
    int n = wave * 32 + ct * 16 + m16;
    #pragma unroll
    for (int kc = 0; kc < 4; kc++)
      bf[ct][kc] = *(const short8*)&Wf[n * 128 + kc * 32 + q * 8];
  }
  const int c0 = wave * 32 + m16, c1 = c0 + 16;
  float bias0 = Bv[c0], bias1 = Bv[c1];
  float aw0 = 0.f, aw1 = 0.f;
  if (LOGIT) { aw0 = attW[c0]; aw1 = attW[c1]; }
  __syncthreads();

  #pragma unroll
  for (int rt = 0; rt < 8; rt++) {
    int r0 = rt * 16;
    // A[m][k]: m = lane&15, k = quad*8+j -> contiguous 16B in LDS
    short8 af[4];
    #pragma unroll
    for (int kc = 0; kc < 4; kc++)
      af[kc] = *(const short8*)&Xs[(r0 + m16) * 136 + kc * 32 + q * 8];
    f32x4 acc0 = {0.f, 0.f, 0.f, 0.f}, acc1 = {0.f, 0.f, 0.f, 0.f};
    #pragma unroll
    for (int kc = 0; kc < 4; kc++) {
      acc0 = __builtin_amdgcn_mfma_f32_16x16x32_bf16(af[kc], bf[0][kc], acc0, 0, 0, 0);
      acc1 = __builtin_amdgcn_mfma_f32_16x16x32_bf16(af[kc], bf[1][kc], acc1, 0, 0, 0);
    }
    // D: col = lane&15 (+ct*16), row = quad*4 + t
    #pragma unroll
    for (int t = 0; t < 4; t++) {
      int rloc = r0 + q * 4 + t;
      float v0 = acc0[t] + bias0;
      float v1 = acc1[t] + bias1;
      if (ACT == 1) {
        v0 = v0 > 0.f ? v0 : 0.01f * v0;
        v1 = v1 > 0.f ? v1 : 0.01f * v1;
      }
      int o = (row0 + rloc) * 128;
      Y[o + c0] = v0;
      Y[o + c1] = v1;
      if (LOGIT) {
        // row-dot partial: reduce across m16 (16-lane groups), one slot per (wave,row)
        float p = v0 * aw0 + v1 * aw1;
        p += __shfl_xor(p, 1, 64);
        p += __shfl_xor(p, 2, 64);
        p += __shfl_xor(p, 4, 64);
        p += __shfl_xor(p, 8, 64);
        if (m16 == 0) rowL[wave * 128 + rloc] = p;
      }
    }
  }
  if (LOGIT) {
    __syncthreads();
    if (tid < 128)
      Lout[row0 + tid] = rowL[tid] + rowL[128 + tid] + rowL[256 + tid] + rowL[384 + tid] + attb[0];
  }
}

// ---------------- segment softmax over logits (tiny: L-only) ----------------
// In: L = logits. Out: L = a = e*wp/max(Swp,1e-3*Z); zero meanA/m2A slice; segsa.
template<bool WA>
__global__ __launch_bounds__(256) void k_soft(float* __restrict__ L,
                                              const float* __restrict__ wp,
                                              const int* __restrict__ beg,
                                              float* __restrict__ meanA,
                                              float* __restrict__ m2A,
                                              float* __restrict__ segsa,
                                              float* __restrict__ a_out) {
  const int s = blockIdx.x;
  const int b = beg[s], e = beg[s + 1];
  const int tid = threadIdx.x, lane = tid & 63, wv = tid >> 6;
  __shared__ float rmax[4], rse[4], rsw[4];

  float vmax = -3.4e38f;
  for (int r = b + tid; r < e; r += 256) vmax = fmaxf(vmax, L[r]);
  #pragma unroll
  for (int o = 32; o > 0; o >>= 1) vmax = fmaxf(vmax, __shfl_xor(vmax, o, 64));
  if (lane == 0) rmax[wv] = vmax;
  __syncthreads();
  const float m = fmaxf(fmaxf(rmax[0], rmax[1]), fmaxf(rmax[2], rmax[3]));

  float se = 0.f, sw = 0.f;
  for (int r = b + tid; r < e; r += 256) {
    float ew = __expf(L[r] - m);
    float aw_ = ew * wp[r];
    se += ew; sw += aw_;
    L[r] = aw_;
  }
  #pragma unroll
  for (int o = 32; o > 0; o >>= 1) { se += __shfl_xor(se, o, 64); sw += __shfl_xor(sw, o, 64); }
  if (lane == 0) { rse[wv] = se; rsw[wv] = sw; }
  __syncthreads();
  const float Z = rse[0] + rse[1] + rse[2] + rse[3];
  const float Swp = rsw[0] + rsw[1] + rsw[2] + rsw[3];
  const float invd = 1.f / fmaxf(Swp, 1e-3f * Z);

  for (int r = b + tid; r < e; r += 256) {
    float a = L[r] * invd;
    L[r] = a;
    if (WA) a_out[r] = a;
  }
  if (tid < 128) meanA[s * 128 + tid] = 0.f;
  else           m2A[s * 128 + tid - 128] = 0.f;
  if (tid == 0) segsa[s] = Swp * invd;
}

// ---------------- per-channel weighted sums (full grid, run-flush atomics) ----------------
__global__ __launch_bounds__(256) void k_chansum(const float* __restrict__ X,
                                                 const float* __restrict__ L,
                                                 const int* __restrict__ seg,
                                                 float* __restrict__ meanA,
                                                 float* __restrict__ m2A) {
  const int base = blockIdx.x * 128;
  const int c = threadIdx.x & 127, half = threadIdx.x >> 7;
  float sax = 0.f, sax2 = 0.f;
  int cur = -1;
  for (int rr = half; rr < 128; rr += 2) {
    int r = base + rr;
    int s = seg[r];
    if (s != cur) {
      if (cur >= 0) { atomicAdd(&meanA[cur * 128 + c], sax); atomicAdd(&m2A[cur * 128 + c], sax2); }
      sax = 0.f; sax2 = 0.f; cur = s;
    }
    float a = L[r];
    float x = X[r * 128 + c];
    float ax = a * x;
    sax += ax;
    sax2 += ax * x;
  }
  if (cur >= 0) { atomicAdd(&meanA[cur * 128 + c], sax); atomicAdd(&m2A[cur * 128 + c], sax2); }
}

// ---------------- block-end apply: H = relu((X-mean)*istd) + H ----------------
__global__ __launch_bounds__(256) void k_apply(const float* __restrict__ X,
                                               float* __restrict__ H,
                                               const int* __restrict__ seg,
                                               const float* __restrict__ meanA,
                                               const float* __restrict__ m2A,
                                               const float* __restrict__ segsa) {
  const int base4 = blockIdx.x * 4096;   // block covers 128 rows = 4096 float4
  #pragma unroll 4
  for (int i = 0; i < 16; i++) {
    int f4 = base4 + i * 256 + threadIdx.x;
    int r = f4 >> 5, c4 = (f4 & 31) << 2;
    int s = seg[r];
    float sa = segsa[s];
    float4 x = ((const float4*)X)[f4];
    float4 mn = *(const float4*)&meanA[s * 128 + c4];
    float4 m2 = *(const float4*)&m2A[s * 128 + c4];
    float4 h = ((const float4*)H)[f4];
    x.x = fmaxf((x.x - mn.x) * rsqrtf(m2.x + (sa - 2.f) * mn.x * mn.x + 1e-3f), 0.f) + h.x;
    x.y = fmaxf((x.y - mn.y) * rsqrtf(m2.y + (sa - 2.f) * mn.y * mn.y + 1e-3f), 0.f) + h.y;
    x.z = fmaxf((x.z - mn.z) * rsqrtf(m2.z + (sa - 2.f) * mn.z * mn.z + 1e-3f), 0.f) + h.z;
    x.w = fmaxf((x.w - mn.w) * rsqrtf(m2.w + (sa - 2.f) * mn.w * mn.w + 1e-3f), 0.f) + h.w;
    ((float4*)H)[f4] = x;
  }
}

// ---------------- launch ----------------
extern "C" void kernel_launch(void* const* d_in, const int* in_sizes, int n_in,
                              void* d_out, int out_size, void* d_ws, size_t ws_size,
                              hipStream_t stream) {
  const float* x     = (const float*)d_in[0];
  const int*   seg   = (const int*)d_in[1];
  const float* wp    = (const float*)d_in[2];
  const float* Win0  = (const float*)d_in[3];
  const float* bin0  = (const float*)d_in[4];
  const float* Wr    = (const float*)d_in[5];
  const float* br    = (const float*)d_in[6];
  const float* convW = (const float*)d_in[7];
  const float* convb = (const float*)d_in[8];
  const float* attW  = (const float*)d_in[9];
  const float* attb  = (const float*)d_in[10];
  const float* outW  = (const float*)d_in[11];
  const float* outb  = (const float*)d_in[12];

  float* A0    = (float*)d_ws;                        // h master (64 MB)
  float* L     = A0 + (size_t)N_PTS * 128;            // logits -> a
  float* meanA = L + N_PTS;                           // [128][128]
  float* m2A   = meanA + 128 * 128;                   // [128][128]
  float* segsa = m2A + 128 * 128;                     // [128]
  int*   beg   = (int*)(segsa + 128);                 // [NSEG+1]
  u16*   Wf    = (u16*)(beg + NSEG + 2);              // 18 packed matrices
  float* A1    = (float*)d_out;                       // pre-norm tile / final h
  float* a_out = (float*)d_out + (size_t)N_PTS * 128; // last_a

  k_bounds2<<<N_PTS / 256, 256, 0, stream>>>(seg, beg);
  k_wpack<<<18, 256, 0, stream>>>(Wr, convW, outW, Wf);
  k_in0<<<N_PTS * 128 / 256, 256, 0, stream>>>(x, Win0, bin0, A0);

  for (int i = 0; i < 4; i++)  // input Mlp (all effectively lrelu'd)
    k_gemm<1, false, false><<<N_PTS / 128, 256, 0, stream>>>(
        A0, Wf + i * 16384, br + i * 128, A0,
        nullptr, nullptr, nullptr, nullptr, nullptr, nullptr, nullptr);

  for (int li = 0; li < 6; li++) {
    const float* aW0 = attW + (li * 2 + 0) * 128;
    const float* aW1 = attW + (li * 2 + 1) * 128;
    // inner 1: GEMM h->T with logits
    k_gemm<0, true, false><<<N_PTS / 128, 256, 0, stream>>>(
        A0, Wf + (4 + 2 * li) * 16384, convb + (li * 2 + 0) * 128, A1,
        aW0, attb + (li * 2 + 0), L, nullptr, nullptr, nullptr, nullptr);
    k_soft<false><<<NSEG, 256, 0, stream>>>(L, wp, beg, meanA, m2A, segsa, nullptr);
    k_chansum<<<N_PTS / 128, 256, 0, stream>>>(A1, L, seg, meanA, m2A);
    // inner 2: GEMM T->T with fused normalize-1 on input, logits out
    k_gemm<0, true, true><<<N_PTS / 128, 256, 0, stream>>>(
        A1, Wf + (4 + 2 * li + 1) * 16384, convb + (li * 2 + 1) * 128, A1,
        aW1, attb + (li * 2 + 1), L, seg, meanA, m2A, segsa);
    if (li == 5)
      k_soft<true><<<NSEG, 256, 0, stream>>>(L, wp, beg, meanA, m2A, segsa, a_out);
    else
      k_soft<false><<<NSEG, 256, 0, stream>>>(L, wp, beg, meanA, m2A, segsa, nullptr);
    k_chansum<<<N_PTS / 128, 256, 0, stream>>>(A1, L, seg, meanA, m2A);
    // block end: h = relu(norm(T)) + h
    k_apply<<<N_PTS / 128, 256, 0, stream>>>(A1, A0, seg, meanA, m2A, segsa);
  }

  k_gemm<1, false, false><<<N_PTS / 128, 256, 0, stream>>>(
      A0, Wf + 16 * 16384, outb, A0,
      nullptr, nullptr, nullptr, nullptr, nullptr, nullptr, nullptr);
  k_gemm<0, false, false><<<N_PTS / 128, 256, 0, stream>>>(
      A0, Wf + 17 * 16384, outb + 128, A1,
      nullptr, nullptr, nullptr, nullptr, nullptr, nullptr, nullptr);
}

// Round 4
// 989.490 us; speedup vs baseline: 2.5281x; 1.1784x over previous
//
#include <hip/hip_runtime.h>

#define N_PTS 131072
#define NSEG 128

typedef unsigned short u16;
typedef __attribute__((ext_vector_type(8))) short short8;
typedef __attribute__((ext_vector_type(8))) unsigned short ushort8;
typedef __attribute__((ext_vector_type(4))) float f32x4;

__device__ __forceinline__ float b2f(u16 u) {
  union { unsigned v; float f; } x; x.v = ((unsigned)u) << 16; return x.f;
}
__device__ __forceinline__ u16 f2b(float f) {
  unsigned u = __float_as_uint(f);
  u += 0x7FFFu + ((u >> 16) & 1u);   // RNE
  return (u16)(u >> 16);
}

// ---------------- segment bounds: sorted boundary scan ----------------
__global__ __launch_bounds__(256) void k_bounds2(const int* __restrict__ seg, int* __restrict__ beg) {
  int i = blockIdx.x * 256 + threadIdx.x;
  int sc = seg[i];
  int sp = (i == 0) ? -1 : seg[i - 1];
  for (int s = sp + 1; s <= sc; s++) beg[s] = i;
  if (i == N_PTS - 1)
    for (int s = sc + 1; s <= NSEG; s++) beg[s] = N_PTS;
}

// ---------------- pack 18 weight matrices, transposed bf16 ----------------
__global__ __launch_bounds__(256) void k_wpack(const float* __restrict__ Wr,
                                               const float* __restrict__ convW,
                                               const float* __restrict__ outW,
                                               u16* __restrict__ Wf) {
  int mat = blockIdx.x;
  const float* W = (mat < 4) ? (Wr + mat * 16384)
                 : (mat < 16) ? (convW + (mat - 4) * 16384)
                              : (outW + (mat - 16) * 16384);
  u16* dst = Wf + mat * 16384;
  for (int t = threadIdx.x; t < 16384; t += 256) {
    int n = t >> 7, k = t & 127;
    dst[t] = f2b(W[k * 128 + n]);
  }
}

// ---------------- input layer ----------------
__global__ __launch_bounds__(256) void k_in0(const float* __restrict__ x,
                                             const float* __restrict__ W0,
                                             const float* __restrict__ b0,
                                             u16* __restrict__ Yb) {
  int gid = blockIdx.x * 256 + threadIdx.x;
  int n = gid >> 7, c = gid & 127;
  float acc = b0[c];
  acc += x[n * 3 + 0] * W0[c];
  acc += x[n * 3 + 1] * W0[128 + c];
  acc += x[n * 3 + 2] * W0[256 + c];
  Yb[gid] = f2b(acc > 0.f ? acc : 0.01f * acc);
}

// ---------------- GEMM [N,128]@[128,128] ----------------
// IN: 0 fp32 plain, 1 bf16 plain (pure copy), 2 bf16 norm+relu, 3 bf16 norm+relu+res.
// ACT: 0 none, 1 lrelu.  OUT: 0 fp32 Yf, 1 bf16 Yb.  LOGIT: Lout = Y·attW+attb.
// WH (IN==3): write hn back to Hout.  In-place safe per block.
template<int IN, int ACT, int OUT, bool LOGIT, bool WH>
__global__ __launch_bounds__(256) void k_gemm(const void* Xv,
                                              const u16* __restrict__ Wf,
                                              const float* __restrict__ Bv,
                                              float* Yf, u16* Yb,
                                              const float* __restrict__ attW,
                                              const float* __restrict__ attb,
                                              float* __restrict__ Lout,
                                              const int* __restrict__ seg,
                                              const float* __restrict__ meanA,
                                              const float* __restrict__ m2A,
                                              const float* __restrict__ segsa,
                                              const float* __restrict__ Hin,
                                              float* __restrict__ Hout) {
  __shared__ u16 Xs[128 * 136];   // +8 pad: 2-way bank alias (free)
  __shared__ float rowL[512];
  const int tid = threadIdx.x;
  const int wave = tid >> 6, lane = tid & 63;
  const int q = lane >> 4, m16 = lane & 15;
  const int row0 = blockIdx.x * 128;

  if (IN == 0) {
    const float4* X4 = (const float4*)((const float*)Xv + (size_t)row0 * 128);
    #pragma unroll
    for (int i = 0; i < 16; i++) {
      int f4 = i * 256 + tid;
      int rloc = f4 >> 5, c4 = (f4 & 31) << 2;
      float4 v = X4[f4];
      ushort4 h;
      h.x = f2b(v.x); h.y = f2b(v.y); h.z = f2b(v.z); h.w = f2b(v.w);
      *(ushort4*)&Xs[rloc * 136 + c4] = h;
    }
  } else {
    const u16* Xb = (const u16*)Xv + (size_t)row0 * 128;
    #pragma unroll
    for (int i = 0; i < 8; i++) {
      int e8 = i * 2048 + tid * 8;
      int rloc = e8 >> 7, c8 = e8 & 127;
      ushort8 raw = *(const ushort8*)&Xb[rloc * 128 + c8];
      if (IN == 1) {
        *(ushort8*)&Xs[rloc * 136 + c8] = raw;
      } else {
        int gr = row0 + rloc;
        int s = seg[gr];
        float sa = segsa[s];
        float4 mn0 = *(const float4*)&meanA[s * 128 + c8];
        float4 mn1 = *(const float4*)&meanA[s * 128 + c8 + 4];
        float4 q0 = *(const float4*)&m2A[s * 128 + c8];
        float4 q1 = *(const float4*)&m2A[s * 128 + c8 + 4];
        float mn[8] = {mn0.x, mn0.y, mn0.z, mn0.w, mn1.x, mn1.y, mn1.z, mn1.w};
        float qq[8] = {q0.x, q0.y, q0.z, q0.w, q1.x, q1.y, q1.z, q1.w};
        float v[8];
        #pragma unroll
        for (int j = 0; j < 8; j++) {
          float xv = b2f(raw[j]);
          float m = mn[j];
          v[j] = fmaxf((xv - m) * rsqrtf(qq[j] + (sa - 2.f) * m * m + 1e-3f), 0.f);
        }
        if (IN == 3) {
          float4 h0 = *(const float4*)&Hin[(size_t)gr * 128 + c8];
          float4 h1 = *(const float4*)&Hin[(size_t)gr * 128 + c8 + 4];
          v[0] += h0.x; v[1] += h0.y; v[2] += h0.z; v[3] += h0.w;
          v[4] += h1.x; v[5] += h1.y; v[6] += h1.z; v[7] += h1.w;
          if (WH) {
            float4 w0 = {v[0], v[1], v[2], v[3]};
            float4 w1 = {v[4], v[5], v[6], v[7]};
            *(float4*)&Hout[(size_t)gr * 128 + c8] = w0;
            *(float4*)&Hout[(size_t)gr * 128 + c8 + 4] = w1;
          }
        }
        ushort8 ob;
        #pragma unroll
        for (int j = 0; j < 8; j++) ob[j] = f2b(v[j]);
        *(ushort8*)&Xs[rloc * 136 + c8] = ob;
      }
    }
  }

  short8 bf[2][4];
  #pragma unroll
  for (int ct = 0; ct < 2; ct++) {
    int n = wave * 32 + ct * 16 + m16;
    #pragma unroll
    for (int kc = 0; kc < 4; kc++)
      bf[ct][kc] = *(const short8*)&Wf[n * 128 + kc * 32 + q * 8];
  }
  const int c0 = wave * 32 + m16, c1 = c0 + 16;
  float bias0 = Bv[c0], bias1 = Bv[c1];
  float aw0 = 0.f, aw1 = 0.f;
  if (LOGIT) { aw0 = attW[c0]; aw1 = attW[c1]; }
  __syncthreads();

  #pragma unroll
  for (int rt = 0; rt < 8; rt++) {
    int r0 = rt * 16;
    short8 af[4];
    #pragma unroll
    for (int kc = 0; kc < 4; kc++)
      af[kc] = *(const short8*)&Xs[(r0 + m16) * 136 + kc * 32 + q * 8];
    f32x4 acc0 = {0.f, 0.f, 0.f, 0.f}, acc1 = {0.f, 0.f, 0.f, 0.f};
    #pragma unroll
    for (int kc = 0; kc < 4; kc++) {
      acc0 = __builtin_amdgcn_mfma_f32_16x16x32_bf16(af[kc], bf[0][kc], acc0, 0, 0, 0);
      acc1 = __builtin_amdgcn_mfma_f32_16x16x32_bf16(af[kc], bf[1][kc], acc1, 0, 0, 0);
    }
    #pragma unroll
    for (int t = 0; t < 4; t++) {
      int rloc = r0 + q * 4 + t;
      float v0 = acc0[t] + bias0;
      float v1 = acc1[t] + bias1;
      if (ACT == 1) {
        v0 = v0 > 0.f ? v0 : 0.01f * v0;
        v1 = v1 > 0.f ? v1 : 0.01f * v1;
      }
      size_t o = (size_t)(row0 + rloc) * 128;
      if (OUT == 0) { Yf[o + c0] = v0; Yf[o + c1] = v1; }
      else          { Yb[o + c0] = f2b(v0); Yb[o + c1] = f2b(v1); }
      if (LOGIT) {
        float p = v0 * aw0 + v1 * aw1;
        p += __shfl_xor(p, 1, 64);
        p += __shfl_xor(p, 2, 64);
        p += __shfl_xor(p, 4, 64);
        p += __shfl_xor(p, 8, 64);
        if (m16 == 0) rowL[wave * 128 + rloc] = p;
      }
    }
  }
  if (LOGIT) {
    __syncthreads();
    if (tid < 128)
      Lout[row0 + tid] = rowL[tid] + rowL[128 + tid] + rowL[256 + tid] + rowL[384 + tid] + attb[0];
  }
}

// ---------------- segment softmax over logits ----------------
template<bool WA>
__global__ __launch_bounds__(1024) void k_soft(float* __restrict__ L,
                                               const float* __restrict__ wp,
                                               const int* __restrict__ beg,
                                               float* __restrict__ meanA,
                                               float* __restrict__ m2A,
                                               float* __restrict__ segsa,
                                               float* __restrict__ a_out) {
  const int s = blockIdx.x;
  const int b = beg[s], e = beg[s + 1];
  const int tid = threadIdx.x, lane = tid & 63, wv = tid >> 6;
  __shared__ float redM[16], redA[16], redB[16];

  float vmax = -3.4e38f;
  for (int r = b + tid; r < e; r += 1024) vmax = fmaxf(vmax, L[r]);
  #pragma unroll
  for (int o = 32; o > 0; o >>= 1) vmax = fmaxf(vmax, __shfl_xor(vmax, o, 64));
  if (lane == 0) redM[wv] = vmax;
  __syncthreads();
  float m = -3.4e38f;
  #pragma unroll
  for (int i = 0; i < 16; i++) m = fmaxf(m, redM[i]);

  float se = 0.f, sw = 0.f;
  for (int r = b + tid; r < e; r += 1024) {
    float ew = __expf(L[r] - m);
    float aw_ = ew * wp[r];
    se += ew; sw += aw_;
    L[r] = aw_;
  }
  #pragma unroll
  for (int o = 32; o > 0; o >>= 1) { se += __shfl_xor(se, o, 64); sw += __shfl_xor(sw, o, 64); }
  if (lane == 0) { redA[wv] = se; redB[wv] = sw; }
  __syncthreads();
  float Z = 0.f, Swp = 0.f;
  #pragma unroll
  for (int i = 0; i < 16; i++) { Z += redA[i]; Swp += redB[i]; }
  const float invd = 1.f / fmaxf(Swp, 1e-3f * Z);

  for (int r = b + tid; r < e; r += 1024) {
    float a = L[r] * invd;
    L[r] = a;
    if (WA) a_out[r] = a;
  }
  if (tid < 128) meanA[s * 128 + tid] = 0.f;
  else if (tid < 256) m2A[s * 128 + tid - 128] = 0.f;
  if (tid == 0) segsa[s] = Swp * invd;
}

// ---------------- per-channel weighted sums (bf16 X, run-flush atomics) ----------------
__global__ __launch_bounds__(256) void k_chansum(const u16* __restrict__ Xb,
                                                 const float* __restrict__ L,
                                                 const int* __restrict__ seg,
                                                 float* __restrict__ meanA,
                                                 float* __restrict__ m2A) {
  const int base = blockIdx.x * 128;
  const int c = threadIdx.x & 127, half = threadIdx.x >> 7;
  float sax = 0.f, sax2 = 0.f;
  int cur = -1;
  for (int rr = half; rr < 128; rr += 2) {
    int r = base + rr;
    int s = seg[r];
    if (s != cur) {
      if (cur >= 0) { atomicAdd(&meanA[cur * 128 + c], sax); atomicAdd(&m2A[cur * 128 + c], sax2); }
      sax = 0.f; sax2 = 0.f; cur = s;
    }
    float a = L[r];
    float x = b2f(Xb[(size_t)r * 128 + c]);
    float ax = a * x;
    sax += ax;
    sax2 += ax * x;
  }
  if (cur >= 0) { atomicAdd(&meanA[cur * 128 + c], sax); atomicAdd(&m2A[cur * 128 + c], sax2); }
}

// ---------------- launch ----------------
extern "C" void kernel_launch(void* const* d_in, const int* in_sizes, int n_in,
                              void* d_out, int out_size, void* d_ws, size_t ws_size,
                              hipStream_t stream) {
  const float* x     = (const float*)d_in[0];
  const int*   seg   = (const int*)d_in[1];
  const float* wp    = (const float*)d_in[2];
  const float* Win0  = (const float*)d_in[3];
  const float* bin0  = (const float*)d_in[4];
  const float* Wr    = (const float*)d_in[5];
  const float* br    = (const float*)d_in[6];
  const float* convW = (const float*)d_in[7];
  const float* convb = (const float*)d_in[8];
  const float* attW  = (const float*)d_in[9];
  const float* attb  = (const float*)d_in[10];
  const float* outW  = (const float*)d_in[11];
  const float* outb  = (const float*)d_in[12];

  float* A0    = (float*)d_ws;                  // residual h, fp32 (64 MiB)
  float* L     = A0 + (size_t)N_PTS * 128;
  float* meanA = L + N_PTS;
  float* m2A   = meanA + 128 * 128;
  float* segsa = m2A + 128 * 128;
  int*   beg   = (int*)(segsa + 128);
  u16*   Wf    = (u16*)(beg + NSEG + 2);

  u16*   Tb    = (u16*)d_out;                   // bf16 scratch (32 MiB, dead at end)
  float* Of    = (float*)d_out;                 // final h (fp32)
  float* a_out = (float*)d_out + (size_t)N_PTS * 128;

  const int GB = N_PTS / 128;

  k_bounds2<<<N_PTS / 256, 256, 0, stream>>>(seg, beg);
  k_wpack<<<18, 256, 0, stream>>>(Wr, convW, outW, Wf);
  k_in0<<<N_PTS * 128 / 256, 256, 0, stream>>>(x, Win0, bin0, Tb);

  for (int i = 0; i < 3; i++)
    k_gemm<1, 1, 1, false, false><<<GB, 256, 0, stream>>>(
        Tb, Wf + i * 16384, br + i * 128, nullptr, Tb,
        nullptr, nullptr, nullptr, nullptr, nullptr, nullptr, nullptr, nullptr, nullptr);
  k_gemm<1, 1, 0, false, false><<<GB, 256, 0, stream>>>(
      Tb, Wf + 3 * 16384, br + 3 * 128, A0, nullptr,
      nullptr, nullptr, nullptr, nullptr, nullptr, nullptr, nullptr, nullptr, nullptr);

  for (int li = 0; li < 6; li++) {
    const u16* W1 = Wf + (4 + 2 * li) * 16384;
    const float* aW0 = attW + (li * 2 + 0) * 128;
    const float* aW1 = attW + (li * 2 + 1) * 128;
    if (li == 0)
      k_gemm<0, 0, 1, true, false><<<GB, 256, 0, stream>>>(
          A0, W1, convb + (li * 2 + 0) * 128, nullptr, Tb,
          aW0, attb + (li * 2 + 0), L, nullptr, nullptr, nullptr, nullptr, nullptr, nullptr);
    else
      k_gemm<3, 0, 1, true, true><<<GB, 256, 0, stream>>>(
          Tb, W1, convb + (li * 2 + 0) * 128, nullptr, Tb,
          aW0, attb + (li * 2 + 0), L, seg, meanA, m2A, segsa, A0, A0);
    k_soft<false><<<NSEG, 1024, 0, stream>>>(L, wp, beg, meanA, m2A, segsa, nullptr);
    k_chansum<<<GB, 256, 0, stream>>>(Tb, L, seg, meanA, m2A);
    k_gemm<2, 0, 1, true, false><<<GB, 256, 0, stream>>>(
        Tb, W1 + 16384, convb + (li * 2 + 1) * 128, nullptr, Tb,
        aW1, attb + (li * 2 + 1), L, seg, meanA, m2A, segsa, nullptr, nullptr);
    if (li == 5)
      k_soft<true><<<NSEG, 1024, 0, stream>>>(L, wp, beg, meanA, m2A, segsa, a_out);
    else
      k_soft<false><<<NSEG, 1024, 0, stream>>>(L, wp, beg, meanA, m2A, segsa, nullptr);
    k_chansum<<<GB, 256, 0, stream>>>(Tb, L, seg, meanA, m2A);
  }

  k_gemm<3, 1, 0, false, false><<<GB, 256, 0, stream>>>(
      Tb, Wf + 16 * 16384, outb, A0, nullptr,
      nullptr, nullptr, nullptr, seg, meanA, m2A, segsa, A0, nullptr);
  k_gemm<0, 0, 0, false, false><<<GB, 256, 0, stream>>>(
      A0, Wf + 17 * 16384, outb + 128, Of, nullptr,
      nullptr, nullptr, nullptr, nullptr, nullptr, nullptr, nullptr, nullptr, nullptr);
}